// Round 1
// 878.617 us; speedup vs baseline: 1.2362x; 1.2362x over previous
//
#include <hip/hip_runtime.h>
#include <hip/hip_bf16.h>

typedef unsigned short u16;
typedef unsigned int   u32;

namespace {
constexpr int Kc  = 24;
constexpr int CPJ = 128;
constexpr int TD  = 128;
constexpr int Tc  = 4096;
constexpr int NT  = 8;    // consecutive t per block (write-coalescing group)
constexpr float EPS   = 1e-5f;
constexpr float SCALE = 0.08838834764831845f;  // 128^-0.5

constexpr int AS = 136;  // bf16 row stride for 32-row token-major tiles
constexpr int VS = 40;   // row stride for vT[128][.] and Pb[32][.]
constexpr int SS = 36;   // f32 row stride for scores

// packed-weight section offsets (bf16 elems): fragment chunks of 512 elems,
// chunk (ntile,kstep): elem[lane*8+j] = W[kstep*32+(lane>>4)*8+j][ntile*16+(lane&15)]
constexpr int OFF_TOK  = 0;
constexpr int OFF_QKV  = 16384;
constexpr int OFF_PROJ = 65536;
constexpr int OFF_FROM = 81920;
constexpr int WTOT     = 98304;

typedef __attribute__((ext_vector_type(8))) short short8;
typedef __attribute__((ext_vector_type(4))) float f32x4;

__device__ u16 g_wpack[WTOT];

__device__ __forceinline__ float b2f(u16 u) {
  union { u32 i; float f; } c; c.i = ((u32)u) << 16; return c.f;
}
__device__ __forceinline__ u16 f2b(float f) {
  __hip_bfloat16 h = __float2bfloat16(f);
  u16 u; __builtin_memcpy(&u, &h, 2); return u;
}
template <bool F32> __device__ __forceinline__ float ld1(const void* p, int i) {
  return F32 ? ((const float*)p)[i] : b2f(((const u16*)p)[i]);
}
__device__ __forceinline__ f32x4 mfma16(short8 a, short8 b, f32x4 c) {
  return __builtin_amdgcn_mfma_f32_16x16x32_bf16(a, b, c, 0, 0, 0);
}
// channel->slab-slot swizzle: XOR bit4 with (row>>2)&1 so the 4 quads of the
// final-GEMM staging store hit 2 disjoint 16-bank sets (2-way = free).
__device__ __forceinline__ int slot(int c) { return c ^ (((c >> 9) & 1) << 4); }

// block-uniform dtype sniff: f32 storage -> low mantissa words decode huge as bf16
__device__ bool sniff_f32(const u16* x, float* red, int tid) {
  float m = 0.f;
  for (int i = tid; i < 1024; i += 256) m = fmaxf(m, fabsf(b2f(x[i])));
  red[tid] = m;
  __syncthreads();
  if (tid < 32) {
    float mm = red[tid];
    for (int s = tid + 32; s < 256; s += 32) mm = fmaxf(mm, red[s]);
    red[tid] = mm;
  }
  __syncthreads();
  if (tid == 0) {
    float mm = red[0];
    for (int s = 1; s < 32; ++s) mm = fmaxf(mm, red[s]);
    red[0] = mm;
  }
  __syncthreads();
  return red[0] > 1e8f;
}
}  // namespace

// ---------------- weight packing kernel (runs every launch) ----------------
template <bool F32>
__device__ void pack_body(const void* Wtok, const void* Wqkv, const void* Wproj,
                          const void* Wfrom, int gid) {
  const void* W; int Nw, base;
  if (gid < OFF_QKV)       { W = Wtok;  Nw = 128; base = OFF_TOK;  }
  else if (gid < OFF_PROJ) { W = Wqkv;  Nw = 384; base = OFF_QKV;  }
  else if (gid < OFF_FROM) { W = Wproj; Nw = 128; base = OFF_PROJ; }
  else                     { W = Wfrom; Nw = 128; base = OFF_FROM; }
  const int e = gid - base, chunk = e >> 9, rem = e & 511, lane = rem >> 3, j = rem & 7;
  const int ntile = chunk >> 2, kstep = chunk & 3;
  const int n = ntile * 16 + (lane & 15);
  const int k = kstep * 32 + (lane >> 4) * 8 + j;
  g_wpack[gid] = F32 ? f2b(((const float*)W)[k * Nw + n]) : ((const u16*)W)[k * Nw + n];
}

__global__ __launch_bounds__(256) void wan_pack_kernel(
    const void* x, const void* Wtok, const void* Wqkv, const void* Wproj,
    const void* Wfrom) {
  __shared__ float red[256];
  const int tid = threadIdx.x;
  const bool f32m = sniff_f32((const u16*)x, red, tid);
  const int gid = blockIdx.x * 256 + tid;
  if (gid < WTOT) {
    if (f32m) pack_body<true>(Wtok, Wqkv, Wproj, Wfrom, gid);
    else      pack_body<false>(Wtok, Wqkv, Wproj, Wfrom, gid);
  }
}

// ---------------- main kernel ----------------
struct __align__(16) Smem {
  float slab[NT * 3072];  // 96 KiB: x-in / y-out staging, io-dtype, t-major
  u16 xt[32 * AS];        // current-t x tile bf16 (+ residual); rows 24..31 zero
  u16 tokb[32 * AS];      // tok -> later O (attn@v)
  u16 qb[32 * AS];        // q -> later out2
  u16 kb[32 * AS];
  u16 vt[128 * VS];       // v transposed [dim][token]
  u16 Pb[32 * VS];        // probs, K-padded with zeros
  float Sf[32 * SS];      // scores; overlays sniff red[256] + norm partial+rowstat
};                        // total 150528 B -> 1 block/CU

// C[32x128] = A @ Wpacked + bias, C stored bf16 row-major stride AS.
template <bool F32>
__device__ __forceinline__ void gemmA(const u16* A, const u16* wp, const void* bias,
                                      u16* C, int mtile, int wn, int l16, int quad,
                                      int lane) {
  const u16* arow = A + (mtile * 16 + l16) * AS + quad * 8;
  short8 af[4];
  #pragma unroll
  for (int ks = 0; ks < 4; ++ks) af[ks] = *(const short8*)(arow + ks * 32);
  #pragma unroll
  for (int i = 0; i < 4; ++i) {
    const int ntile = wn * 4 + i;
    const float bv = ld1<F32>(bias, ntile * 16 + l16);
    f32x4 acc = {bv, bv, bv, bv};
    #pragma unroll
    for (int ks = 0; ks < 4; ++ks) {
      short8 bf = *(const short8*)(wp + (ntile * 4 + ks) * 512 + lane * 8);
      acc = mfma16(af[ks], bf, acc);
    }
    u16* p = C + (mtile * 16 + quad * 4) * AS + ntile * 16 + l16;
    p[0] = f2b(acc[0]); p[AS] = f2b(acc[1]);
    p[2 * AS] = f2b(acc[2]); p[3 * AS] = f2b(acc[3]);
  }
}

template <bool F32>
__device__ void main_body(Smem& s, int tid, long long xbase, const void* x,
                          const void* btok, const void* gnorm, const void* bqkv,
                          const void* bproj, const void* bfrom, void* y) {
  const int lane = tid & 63, wid = tid >> 6;
  const int l16 = lane & 15, quad = lane >> 4;
  const int mtile = wid & 1, wn = wid >> 1;

  // ---- once: zero Pb (K-pad safety) + xt pad rows ----------------------
  for (int i = tid; i < 32 * VS; i += 256) s.Pb[i] = 0;
  for (int i = tid; i < 8 * AS; i += 256) s.xt[24 * AS + i] = 0;

  // ---- stage x slab [NT][3072] once: 32B contiguous per channel --------
  if (F32) {
    const float* xf = (const float*)x + xbase;
    #pragma unroll
    for (int m = 0; m < 24; ++m) {
      const int gi = tid + 256 * m;          // 0..6143
      const int c = gi >> 1, h = gi & 1;     // channel, float4-half
      const float4 v = ((const float4*)(xf + (long long)c * Tc))[h];
      float* dst = s.slab + (h * 4) * 3072 + slot(c);
      dst[0] = v.x; dst[3072] = v.y; dst[2 * 3072] = v.z; dst[3 * 3072] = v.w;
    }
  } else {
    const u16* xh = (const u16*)x + xbase;
    u16* sl = (u16*)s.slab;
    #pragma unroll
    for (int m = 0; m < 12; ++m) {
      const int c = tid + 256 * m;
      const short8 v = *(const short8*)(xh + (long long)c * Tc);
      u16* dst = sl + slot(c);
      #pragma unroll
      for (int q = 0; q < 8; ++q) dst[q * 3072] = ((const u16*)&v)[q];
    }
  }

  #pragma unroll 1
  for (int j = 0; j < NT; ++j) {
    __syncthreads();  // slab ready / prev iteration fully consumed xt

    // ---- copy slab col j -> xt (bf16 row-major token tile) -------------
    #pragma unroll
    for (int m = 0; m < 3; ++m) {
      const int c4 = (tid + 256 * m) * 4;    // 4 consecutive channels
      const int sb = slot(c4);               // slot() preserves 4-contiguity
      ushort4 o;
      if (F32) {
        const float4 v = *(const float4*)(s.slab + j * 3072 + sb);
        o.x = f2b(v.x); o.y = f2b(v.y); o.z = f2b(v.z); o.w = f2b(v.w);
      } else {
        o = *(const ushort4*)((const u16*)s.slab + j * 3072 + sb);
      }
      *(ushort4*)(s.xt + (c4 >> 7) * AS + (c4 & 127)) = o;
    }
    __syncthreads();

    // ---- tok = xt @ Wtok + btok ----------------------------------------
    gemmA<F32>(s.xt, g_wpack + OFF_TOK, btok, s.tokb, mtile, wn, l16, quad, lane);
    __syncthreads();

    // ---- RMSNorm rows 0..23 (in-place bf16) ----------------------------
    float* partial = s.Sf;        // 192 floats
    float* rowstat = s.Sf + 192;  // 24 floats
    if (tid < 192) {
      const int row = tid >> 3, sub = tid & 7;
      const u16* p = s.tokb + row * AS + sub * 16;
      float ss = 0.f;
      #pragma unroll
      for (int d = 0; d < 16; ++d) { const float v = b2f(p[d]); ss += v * v; }
      partial[tid] = ss;
    }
    __syncthreads();
    if (tid < 24) {
      float ss = 0.f;
      #pragma unroll
      for (int u = 0; u < 8; ++u) ss += partial[tid * 8 + u];
      rowstat[tid] = rsqrtf(ss * (1.0f / TD) + EPS);
    }
    __syncthreads();
    if (tid < 192) {
      const int row = tid >> 3, sub = tid & 7;
      u16* p = s.tokb + row * AS + sub * 16;
      const float rs = rowstat[row];
      #pragma unroll
      for (int d = 0; d < 16; ++d)
        p[d] = f2b(b2f(p[d]) * rs * ld1<F32>(gnorm, sub * 16 + d));
    }
    __syncthreads();

    // ---- qkv = tok @ Wqkv + bqkv; v stored transposed ------------------
    {
      const u16* wp = g_wpack + OFF_QKV;
      const u16* arow = s.tokb + (mtile * 16 + l16) * AS + quad * 8;
      short8 af[4];
      #pragma unroll
      for (int ks = 0; ks < 4; ++ks) af[ks] = *(const short8*)(arow + ks * 32);
      for (int g = 0; g < 3; ++g) {
        #pragma unroll
        for (int i = 0; i < 4; ++i) {
          const int nn = wn + i * 2;       // 0..7 within segment
          const int ntile = g * 8 + nn;    // 0..23
          const float bv = ld1<F32>(bqkv, ntile * 16 + l16);
          f32x4 acc = {bv, bv, bv, bv};
          #pragma unroll
          for (int ks = 0; ks < 4; ++ks) {
            short8 bf = *(const short8*)(wp + (ntile * 4 + ks) * 512 + lane * 8);
            acc = mfma16(af[ks], bf, acc);
          }
          if (g == 2) {
            ushort4 v4 = {f2b(acc[0]), f2b(acc[1]), f2b(acc[2]), f2b(acc[3])};
            *reinterpret_cast<ushort4*>(s.vt + (nn * 16 + l16) * VS + mtile * 16 +
                                        quad * 4) = v4;
          } else {
            u16* dst = g ? s.kb : s.qb;
            u16* p = dst + (mtile * 16 + quad * 4) * AS + nn * 16 + l16;
            p[0] = f2b(acc[0]); p[AS] = f2b(acc[1]);
            p[2 * AS] = f2b(acc[2]); p[3 * AS] = f2b(acc[3]);
          }
        }
      }
    }
    __syncthreads();

    // ---- S = q @ k^T * SCALE (one 16x16 tile per wave) -----------------
    {
      // fragment loads MUST include the per-quad k-offset (+ quad*8)
      const u16* qrow = s.qb + (mtile * 16 + l16) * AS + quad * 8;
      const u16* krow = s.kb + (wn * 16 + l16) * AS + quad * 8;
      f32x4 acc = {0.f, 0.f, 0.f, 0.f};
      #pragma unroll
      for (int ks = 0; ks < 4; ++ks) {
        short8 a = *(const short8*)(qrow + ks * 32);
        short8 b = *(const short8*)(krow + ks * 32);
        acc = mfma16(a, b, acc);
      }
      float* sp = s.Sf + (mtile * 16 + quad * 4) * SS + wn * 16 + l16;
      sp[0] = acc[0] * SCALE; sp[SS] = acc[1] * SCALE;
      sp[2 * SS] = acc[2] * SCALE; sp[3 * SS] = acc[3] * SCALE;
    }
    __syncthreads();

    // ---- softmax rows 0..23 over cols 0..23 -> Pb (bf16, zero-padded) --
    if (tid < 24) {
      const float* sr = s.Sf + tid * SS;
      float mx = -1e30f;
      #pragma unroll
      for (int jj = 0; jj < 24; ++jj) mx = fmaxf(mx, sr[jj]);
      float sum = 0.f; float e[24];
      #pragma unroll
      for (int jj = 0; jj < 24; ++jj) { e[jj] = expf(sr[jj] - mx); sum += e[jj]; }
      const float inv = 1.0f / sum;
      u16* pr = s.Pb + tid * VS;
      #pragma unroll
      for (int jj = 0; jj < 24; ++jj) pr[jj] = f2b(e[jj] * inv);
    }
    __syncthreads();

    // ---- O = P @ v (K=32, single MFMA per tile) -> tokb ----------------
    {
      short8 ap = *(const short8*)(s.Pb + (mtile * 16 + l16) * VS + quad * 8);
      #pragma unroll
      for (int i = 0; i < 4; ++i) {
        const int nt = wn * 4 + i;
        short8 bv = *(const short8*)(s.vt + (nt * 16 + l16) * VS + quad * 8);
        f32x4 acc = {0.f, 0.f, 0.f, 0.f};
        acc = mfma16(ap, bv, acc);
        u16* p = s.tokb + (mtile * 16 + quad * 4) * AS + nt * 16 + l16;
        p[0] = f2b(acc[0]); p[AS] = f2b(acc[1]);
        p[2 * AS] = f2b(acc[2]); p[3 * AS] = f2b(acc[3]);
      }
    }
    __syncthreads();

    // ---- out2 = O @ Wproj + bproj -> qb --------------------------------
    gemmA<F32>(s.tokb, g_wpack + OFF_PROJ, bproj, s.qb, mtile, wn, l16, quad, lane);
    __syncthreads();

    // ---- out3 = out2 @ Wfrom + bfrom; stage y = x + out3 in slab -------
    {
      const u16* arow = s.qb + (mtile * 16 + l16) * AS + quad * 8;
      const u16* wp = g_wpack + OFF_FROM;
      short8 af[4];
      #pragma unroll
      for (int ks = 0; ks < 4; ++ks) af[ks] = *(const short8*)(arow + ks * 32);
      #pragma unroll
      for (int i = 0; i < 4; ++i) {
        const int ntile = wn * 4 + i;
        const float bv = ld1<F32>(bfrom, ntile * 16 + l16);
        f32x4 acc = {bv, bv, bv, bv};
        #pragma unroll
        for (int ks = 0; ks < 4; ++ks) {
          short8 bf = *(const short8*)(wp + (ntile * 4 + ks) * 512 + lane * 8);
          acc = mfma16(af[ks], bf, acc);
        }
        const int row0 = mtile * 16 + quad * 4;
        if (row0 < 24) {
          #pragma unroll
          for (int r = 0; r < 4; ++r) {
            const int row = row0 + r;
            const int cc = ntile * 16 + l16;
            const float res = b2f(s.xt[row * AS + cc]) + acc[r];
            const int ch = row * CPJ + cc;
            if (F32) s.slab[j * 3072 + slot(ch)] = res;
            else     ((u16*)s.slab)[j * 3072 + slot(ch)] = f2b(res);
          }
        }
      }
    }
    // loop-top barrier separates this from next iteration's xt overwrite
  }
  __syncthreads();

  // ---- write out slab -> y: 32B contiguous per channel -----------------
  if (F32) {
    float* yf = (float*)y + xbase;
    #pragma unroll
    for (int m = 0; m < 12; ++m) {
      const int c = tid + 256 * m;
      const int sc = slot(c);
      float4 a, b;
      a.x = s.slab[0 * 3072 + sc]; a.y = s.slab[1 * 3072 + sc];
      a.z = s.slab[2 * 3072 + sc]; a.w = s.slab[3 * 3072 + sc];
      b.x = s.slab[4 * 3072 + sc]; b.y = s.slab[5 * 3072 + sc];
      b.z = s.slab[6 * 3072 + sc]; b.w = s.slab[7 * 3072 + sc];
      float4* dst = (float4*)(yf + (long long)c * Tc);
      dst[0] = a; dst[1] = b;
    }
  } else {
    u16* yh = (u16*)y + xbase;
    const u16* sl = (const u16*)s.slab;
    #pragma unroll
    for (int m = 0; m < 12; ++m) {
      const int c = tid + 256 * m;
      const int sc = slot(c);
      short8 v;
      #pragma unroll
      for (int q = 0; q < 8; ++q) ((u16*)&v)[q] = sl[q * 3072 + sc];
      *(short8*)(yh + (long long)c * Tc) = v;
    }
  }
}

__global__ __launch_bounds__(256, 1) void wan_main_kernel(
    const void* x, const void* btok, const void* gnorm, const void* bqkv,
    const void* bproj, const void* bfrom, void* y) {
  __shared__ Smem s;
  const int tid = threadIdx.x;
  // XCD-aware swizzle over t-octets: 2048 blocks = 8 XCDs x 256 contiguous
  // octets, so adjacent-t blocks share an XCD L2 for read/write line merge.
  const int id = blockIdx.x;
  const int oct = (id & 7) * 256 + (id >> 3);
  const int b = oct >> 9, t0 = (oct & 511) << 3;
  const long long xbase = (long long)b * (Kc * CPJ) * Tc + t0;

  const bool f32m = sniff_f32((const u16*)x, s.Sf, tid);
  if (f32m)
    main_body<true>(s, tid, xbase, x, btok, gnorm, bqkv, bproj, bfrom, y);
  else
    main_body<false>(s, tid, xbase, x, btok, gnorm, bqkv, bproj, bfrom, y);
}

extern "C" void kernel_launch(void* const* d_in, const int* in_sizes, int n_in,
                              void* d_out, int out_size, void* d_ws, size_t ws_size,
                              hipStream_t stream) {
  wan_pack_kernel<<<384, 256, 0, stream>>>(d_in[0], d_in[1], d_in[4], d_in[6],
                                           d_in[8]);
  wan_main_kernel<<<2048, 256, 0, stream>>>(d_in[0], d_in[2], d_in[3], d_in[5],
                                            d_in[7], d_in[9], d_out);
}